// Round 5
// baseline (700.561 us; speedup 1.0000x reference)
//
#include <hip/hip_runtime.h>
#include <hip/hip_cooperative_groups.h>
#include <math.h>

namespace cg = cooperative_groups;

#define IN_DIM 256
#define FDIM 256      // HEADS*HID == OUT == 256
#define HEADS 4
#define NEG 0.2f
#define MAXD 96       // per-node staged edge cap; in-deg ~ Poisson(16)+1, P(>96) ~ 0

typedef __attribute__((ext_vector_type(8))) short bf16x8;
typedef __attribute__((ext_vector_type(8))) unsigned short u16x8;
typedef __attribute__((ext_vector_type(4))) float f32x4;

__device__ __forceinline__ float leaky(float x){ return x > 0.f ? x : NEG * x; }

__device__ __forceinline__ unsigned short f2bf(float f){
  unsigned int u = __float_as_uint(f);
  unsigned int r = u + 0x7fffu + ((u >> 16) & 1u);   // round-to-nearest-even
  return (unsigned short)(r >> 16);
}
__device__ __forceinline__ float bf2f(unsigned short s){
  return __uint_as_float(((unsigned int)s) << 16);
}

__device__ __forceinline__ float4 bcast4(float4 v){
  return make_float4(__shfl(v.x,0,64), __shfl(v.y,0,64), __shfl(v.z,0,64), __shfl(v.w,0,64));
}
__device__ __forceinline__ float comp4(float4 v, int h){
  return h==0 ? v.x : h==1 ? v.y : h==2 ? v.z : v.w;
}

__device__ __forceinline__ void gld_lds16(const void* g, void* l){
  __builtin_amdgcn_global_load_lds((const __attribute__((address_space(1))) unsigned int*)g,
                                   (__attribute__((address_space(3))) unsigned int*)l, 16, 0, 0);
}

// ------------------------- cooperative prep kernel -------------------------
// Grid 256 x 256. Phases: (1) zero deg/fill/als2/ald2 + cast x->bf16 + W transposes,
// (2) degree histogram, (3) per-chunk scan, (4) chunk-partial scan, (5) rowptr, (6) CSR fill.
__global__ void k_coop(const float* __restrict__ x, unsigned short* __restrict__ xb,
                       int castUnits, int M,
                       const float* __restrict__ W1, unsigned short* __restrict__ W1t,
                       const float* __restrict__ W2, unsigned short* __restrict__ W2t,
                       const int* __restrict__ src, const int* __restrict__ dst, int E, int n,
                       int* deg, int* fill, int* tmp, int* partials, int* rowptr, int* col,
                       float* als2, float* ald2){
  cg::grid_group grid = cg::this_grid();
  __shared__ int sm[256];
  int t = threadIdx.x;
  int gt = blockIdx.x * 256 + t;
  const int GSZ = 256 * 256;
  int nb = (n + 255) >> 8;

  // ---- phase 1: zeroing + casts (independent) ----
  for (int i = gt; i < n; i += GSZ){ deg[i] = 0; fill[i] = 0; als2[i] = 0.f; ald2[i] = 0.f; }
  for (int u = gt; u < castUnits; u += GSZ){       // ushort4 units of xb
    int row = u >> 6;
    float4 v = make_float4(0.f, 0.f, 0.f, 0.f);
    if (row < M) v = *(const float4*)(x + (size_t)u * 4);
    ushort4 o;
    o.x = f2bf(v.x); o.y = f2bf(v.y); o.z = f2bf(v.z); o.w = f2bf(v.w);
    *(ushort4*)(xb + (size_t)u * 4) = o;
  }
  for (int u = gt; u < 2 * 65536; u += GSZ){       // W1/W2 transpose-cast
    const float* W = (u < 65536) ? W1 : W2;
    unsigned short* Wt = (u < 65536) ? W1t : W2t;
    int e = u & 65535;
    int k = e >> 8, nn = e & 255;                  // consecutive t -> consecutive nn: coalesced read
    Wt[nn * 256 + k] = f2bf(W[k * 256 + nn]);
  }
  __threadfence();
  grid.sync();

  // ---- phase 2: histogram ----
  for (int e = gt; e < E; e += GSZ) atomicAdd(&deg[dst[e]], 1);
  __threadfence();
  grid.sync();

  // ---- phase 3: per-chunk inclusive scan (chunk b = block b, b < nb) ----
  if (blockIdx.x < nb){
    int i = blockIdx.x * 256 + t;
    int v = (i < n) ? deg[i] + 1 : 0;              // +1: self loop
    sm[t] = v; __syncthreads();
    for (int off = 1; off < 256; off <<= 1){
      int xv = (t >= off) ? sm[t - off] : 0;
      __syncthreads();
      sm[t] += xv;
      __syncthreads();
    }
    if (i < n) tmp[i] = sm[t];
    if (t == 255) partials[blockIdx.x] = sm[255];
  }
  __threadfence();
  grid.sync();

  // ---- phase 4: scan chunk partials (block 0 only; nb <= 256) ----
  if (blockIdx.x == 0){
    int v = (t < nb) ? partials[t] : 0;
    sm[t] = v; __syncthreads();
    for (int off = 1; off < 256; off <<= 1){
      int xv = (t >= off) ? sm[t - off] : 0;
      __syncthreads();
      sm[t] += xv;
      __syncthreads();
    }
    if (t < nb) partials[t] = sm[t] - v;           // exclusive
  }
  __threadfence();
  grid.sync();

  // ---- phase 5: rowptr ----
  for (int i = gt; i < n; i += GSZ){
    int incl = tmp[i] + partials[i >> 8];
    rowptr[i] = incl - (deg[i] + 1);
    if (i == n - 1) rowptr[n] = incl;
  }
  __threadfence();
  grid.sync();

  // ---- phase 6: CSR fill ----
  for (int e = gt; e < E + n; e += GSZ){
    int s, d;
    if (e < E){ s = src[e]; d = dst[e]; } else { s = d = e - E; }
    int pos = atomicAdd(&fill[d], 1);
    col[rowptr[d] + pos] = s;
  }
}

// ------------------------- bf16 MFMA GEMM + fused attention logits -------------------------
// C[M,256] = A[M,256] @ Bt[256,256]^T; epilogue also computes als/ald row dots.
// L==1: by covers heads {2by, 2by+1}; round p == head 2by+p -> exact als1/ald1 write.
// L==2: single head over 256 cols -> atomicAdd partials into als2/ald2.
template<int L>
__global__ __launch_bounds__(256) void k_gemm(const unsigned short* __restrict__ A,
                                              const unsigned short* __restrict__ Bt,
                                              unsigned short* __restrict__ C,
                                              const float* __restrict__ avS, const float* __restrict__ avD,
                                              float* __restrict__ als, float* __restrict__ ald, int nvalid){
  __shared__ __align__(16) unsigned short sh[8192];   // As = sh[0:4096], Bs = sh[4096:8192] (shorts)
  unsigned short* As = sh;
  unsigned short* Bs = sh + 4096;
  int tid = threadIdx.x;
  int lane = tid & 63, wave = tid >> 6;
  int rowBase = blockIdx.x * 128, colBase = blockIdx.y * 128;
  int wr = (wave & 1) * 64, wc = (wave >> 1) * 64;

  f32x4 acc[4][4] = {};
  int c0 = tid, c1 = tid + 256;
  int r0 = c0 >> 2, kc0 = (c0 & 3) * 8;
  int r1 = c1 >> 2, kc1 = (c1 & 3) * 8;
  int m0 = lane & 15, kq = (lane >> 4) * 8;

  for (int k0 = 0; k0 < 256; k0 += 32){
    gld_lds16(A  + (size_t)(rowBase + r0) * 256 + k0 + kc0, (char*)As + c0 * 16);
    gld_lds16(A  + (size_t)(rowBase + r1) * 256 + k0 + kc1, (char*)As + c1 * 16);
    gld_lds16(Bt + (size_t)(colBase + r0) * 256 + k0 + kc0, (char*)Bs + c0 * 16);
    gld_lds16(Bt + (size_t)(colBase + r1) * 256 + k0 + kc1, (char*)Bs + c1 * 16);
    __syncthreads();
    bf16x8 af[4], bfr[4];
    #pragma unroll
    for (int it = 0; it < 4; ++it)
      af[it] = *(const bf16x8*)(As + (wr + it * 16 + m0) * 32 + kq);
    #pragma unroll
    for (int jt = 0; jt < 4; ++jt)
      bfr[jt] = *(const bf16x8*)(Bs + (wc + jt * 16 + m0) * 32 + kq);
    #pragma unroll
    for (int it = 0; it < 4; ++it)
      #pragma unroll
      for (int jt = 0; jt < 4; ++jt)
        acc[it][jt] = __builtin_amdgcn_mfma_f32_16x16x32_bf16(af[it], bfr[jt], acc[it][jt], 0, 0, 0);
    __syncthreads();
  }
  // epilogue: repack C/D frags (col=lane&15, row=(lane>>4)*4+reg) through LDS.
  // round p: cols [colBase+p*64, +64) x 128 rows; stage = sh[row*64 + col_local].
  int cq = lane >> 4, cm = lane & 15;
  #pragma unroll
  for (int p = 0; p < 2; ++p){
    if ((wave >> 1) == p){
      #pragma unroll
      for (int it = 0; it < 4; ++it)
        #pragma unroll
        for (int jt = 0; jt < 4; ++jt)
          #pragma unroll
          for (int r = 0; r < 4; ++r)
            sh[(wr + it * 16 + cq * 4 + r) * 64 + jt * 16 + cm] = f2bf(acc[it][jt][r]);
    }
    __syncthreads();
    // fused attention logits: 2 threads per row, 32 cols each
    {
      int r = tid >> 1, half = tid & 1;
      int rg = rowBase + r;
      const float* aS;
      const float* aD;
      if (L == 1){ aS = avS + (blockIdx.y * 2 + p) * 64; aD = avD + (blockIdx.y * 2 + p) * 64; }
      else       { aS = avS + colBase + p * 64;          aD = avD + colBase + p * 64; }
      float ps = 0.f, pd = 0.f;
      #pragma unroll
      for (int k4 = 0; k4 < 8; ++k4){
        ushort4 hv = *(const ushort4*)(sh + r * 64 + half * 32 + k4 * 4);
        float4 a4 = *(const float4*)(aS + half * 32 + k4 * 4);
        float4 d4 = *(const float4*)(aD + half * 32 + k4 * 4);
        ps += bf2f(hv.x)*a4.x + bf2f(hv.y)*a4.y + bf2f(hv.z)*a4.z + bf2f(hv.w)*a4.w;
        pd += bf2f(hv.x)*d4.x + bf2f(hv.y)*d4.y + bf2f(hv.z)*d4.z + bf2f(hv.w)*d4.w;
      }
      ps += __shfl_xor(ps, 1, 64);
      pd += __shfl_xor(pd, 1, 64);
      if (half == 0 && rg < nvalid){
        if (L == 1){
          als[rg * 4 + blockIdx.y * 2 + p] = ps;
          ald[rg * 4 + blockIdx.y * 2 + p] = pd;
        } else {
          atomicAdd(&als[rg], ps);
          atomicAdd(&ald[rg], pd);
        }
      }
    }
    // C store: 128 rows x 8 segments of 8 shorts = 1024 segments; 256 threads x 4 rounds
    #pragma unroll
    for (int q = 0; q < 4; ++q){
      int id = tid + q * 256;
      int r = id >> 3, sg = id & 7;
      u16x8 v = *(const u16x8*)(sh + r * 64 + sg * 8);
      *(u16x8*)(C + (size_t)(rowBase + r) * 256 + colBase + p * 64 + sg * 8) = v;
    }
    __syncthreads();
  }
}

// ------------------------- layer-1 aggregation: 4 nodes/block, wave per node -------------------------
// softmax without max-subtraction (logits ~ +-3 here; mathematically identical)
__global__ __launch_bounds__(256) void k_agg1(const unsigned short* __restrict__ Hb,
    const float* __restrict__ als, const float* __restrict__ ald,
    const int* __restrict__ rowptr, const int* __restrict__ col,
    const float* __restrict__ b, unsigned short* __restrict__ outb, int n){
  __shared__ __align__(16) int   colS[4][MAXD];
  __shared__ __align__(16) float wS[4][MAXD][4];
  int wave = threadIdx.x >> 6, t = threadIdx.x & 63;
  int i = blockIdx.x * 4 + wave; if (i >= n) i = n - 1;
  int start = rowptr[i];
  int deg = rowptr[i + 1] - start;
  float4 adv = *(const float4*)(ald + (size_t)i * 4);
  bool staged = (deg <= MAXD);

  // phase A: stage col + softmax weights, accumulate per-head sums
  float4 ls = make_float4(0.f, 0.f, 0.f, 0.f);
  if (staged){
    for (int j = t; j < deg; j += 64){
      int s = col[start + j];
      colS[wave][j] = s;
      float4 a = *(const float4*)(als + (size_t)s * 4);
      float4 w = make_float4(__expf(leaky(a.x + adv.x)), __expf(leaky(a.y + adv.y)),
                             __expf(leaky(a.z + adv.z)), __expf(leaky(a.w + adv.w)));
      *(float4*)(&wS[wave][j][0]) = w;
      ls.x += w.x; ls.y += w.y; ls.z += w.z; ls.w += w.w;
    }
  } else {
    for (int j = t; j < deg; j += 64){
      int s = col[start + j];
      float4 a = *(const float4*)(als + (size_t)s * 4);
      ls.x += __expf(leaky(a.x + adv.x)); ls.y += __expf(leaky(a.y + adv.y));
      ls.z += __expf(leaky(a.z + adv.z)); ls.w += __expf(leaky(a.w + adv.w));
    }
  }
  #pragma unroll
  for (int off = 32; off >= 1; off >>= 1) ls = make_float4(
      ls.x + __shfl_down(ls.x, off, 64), ls.y + __shfl_down(ls.y, off, 64),
      ls.z + __shfl_down(ls.z, off, 64), ls.w + __shfl_down(ls.w, off, 64));
  float4 d4 = bcast4(ls);
  __syncthreads();

  // phase C: half-wave per edge, 8 feats/lane, 4 loads in flight
  int e2 = t >> 5, l32 = t & 31;
  int h = l32 >> 3, f = l32 * 8;
  float inv = 1.f / (comp4(d4, h) + 1e-16f);
  const unsigned short* Hrow = Hb + f;
  float a0[8] = {0,0,0,0,0,0,0,0}, a1[8] = {0,0,0,0,0,0,0,0};
  float a2[8] = {0,0,0,0,0,0,0,0}, a3[8] = {0,0,0,0,0,0,0,0};
  if (staged){
    int j = 0;
    for (; j + 7 < deg; j += 8){
      int j0 = j + e2, j1 = j + 2 + e2, j2 = j + 4 + e2, j3 = j + 6 + e2;
      int s0 = colS[wave][j0], s1 = colS[wave][j1], s2 = colS[wave][j2], s3 = colS[wave][j3];
      float w0 = wS[wave][j0][h], w1 = wS[wave][j1][h], w2 = wS[wave][j2][h], w3 = wS[wave][j3][h];
      u16x8 h0 = *(const u16x8*)(Hrow + (size_t)s0 * FDIM);
      u16x8 h1 = *(const u16x8*)(Hrow + (size_t)s1 * FDIM);
      u16x8 h2 = *(const u16x8*)(Hrow + (size_t)s2 * FDIM);
      u16x8 h3 = *(const u16x8*)(Hrow + (size_t)s3 * FDIM);
      #pragma unroll
      for (int k = 0; k < 8; ++k){
        a0[k] += bf2f(h0[k]) * w0; a1[k] += bf2f(h1[k]) * w1;
        a2[k] += bf2f(h2[k]) * w2; a3[k] += bf2f(h3[k]) * w3;
      }
    }
    for (; j < deg; j += 2){
      int jj = j + e2;
      if (jj < deg){
        int s = colS[wave][jj]; float w = wS[wave][jj][h];
        u16x8 hh = *(const u16x8*)(Hrow + (size_t)s * FDIM);
        #pragma unroll
        for (int k = 0; k < 8; ++k) a0[k] += bf2f(hh[k]) * w;
      }
    }
  } else {
    float adh = comp4(adv, h);
    for (int j = e2; j < deg; j += 2){
      int s = col[start + j];
      float w = __expf(leaky(als[(size_t)s * 4 + h] + adh));
      u16x8 hh = *(const u16x8*)(Hrow + (size_t)s * FDIM);
      #pragma unroll
      for (int k = 0; k < 8; ++k) a0[k] += bf2f(hh[k]) * w;
    }
  }
  float r[8];
  #pragma unroll
  for (int k = 0; k < 8; ++k){
    r[k] = (a0[k] + a1[k]) + (a2[k] + a3[k]);
    r[k] += __shfl_down(r[k], 32, 64);
  }
  if (t < 32){
    float4 bA = *(const float4*)(b + f);
    float4 bB = *(const float4*)(b + f + 4);
    float bb[8] = {bA.x, bA.y, bA.z, bA.w, bB.x, bB.y, bB.z, bB.w};
    u16x8 o;
    #pragma unroll
    for (int k = 0; k < 8; ++k){
      float v = r[k] * inv + bb[k];
      v = (v > 0.f) ? v : (__expf(v) - 1.f);    // ELU
      o[k] = f2bf(v);
    }
    *(u16x8*)(outb + (size_t)i * FDIM + f) = o;
  }
}

// ------------------------- layer-2 aggregation: 4 nodes/block, wave per node, fp32 out -------------------------
__global__ __launch_bounds__(256) void k_agg2(const unsigned short* __restrict__ Hb,
    const float* __restrict__ als, const float* __restrict__ ald,
    const int* __restrict__ rowptr, const int* __restrict__ col,
    const float* __restrict__ b, float* __restrict__ out, int n){
  __shared__ __align__(16) int   colS[4][MAXD];
  __shared__ __align__(16) float wS[4][MAXD];
  int wave = threadIdx.x >> 6, t = threadIdx.x & 63;
  int i = blockIdx.x * 4 + wave; if (i >= n) i = n - 1;
  int start = rowptr[i];
  int deg = rowptr[i + 1] - start;
  float adv = ald[i];
  bool staged = (deg <= MAXD);

  float ls = 0.f;
  if (staged){
    for (int j = t; j < deg; j += 64){
      int s = col[start + j];
      colS[wave][j] = s;
      float w = __expf(leaky(als[s] + adv));
      wS[wave][j] = w;
      ls += w;
    }
  } else {
    for (int j = t; j < deg; j += 64) ls += __expf(leaky(als[col[start + j]] + adv));
  }
  #pragma unroll
  for (int off = 32; off >= 1; off >>= 1) ls += __shfl_down(ls, off, 64);
  float inv = 1.f / (__shfl(ls, 0, 64) + 1e-16f);
  __syncthreads();

  int e2 = t >> 5, l32 = t & 31;
  int f = l32 * 8;
  const unsigned short* Hrow = Hb + f;
  float a0[8] = {0,0,0,0,0,0,0,0}, a1[8] = {0,0,0,0,0,0,0,0};
  float a2[8] = {0,0,0,0,0,0,0,0}, a3[8] = {0,0,0,0,0,0,0,0};
  if (staged){
    int j = 0;
    for (; j + 7 < deg; j += 8){
      int j0 = j + e2, j1 = j + 2 + e2, j2 = j + 4 + e2, j3 = j + 6 + e2;
      int s0 = colS[wave][j0], s1 = colS[wave][j1], s2 = colS[wave][j2], s3 = colS[wave][j3];
      float w0 = wS[wave][j0], w1 = wS[wave][j1], w2 = wS[wave][j2], w3 = wS[wave][j3];
      u16x8 h0 = *(const u16x8*)(Hrow + (size_t)s0 * FDIM);
      u16x8 h1 = *(const u16x8*)(Hrow + (size_t)s1 * FDIM);
      u16x8 h2 = *(const u16x8*)(Hrow + (size_t)s2 * FDIM);
      u16x8 h3 = *(const u16x8*)(Hrow + (size_t)s3 * FDIM);
      #pragma unroll
      for (int k = 0; k < 8; ++k){
        a0[k] += bf2f(h0[k]) * w0; a1[k] += bf2f(h1[k]) * w1;
        a2[k] += bf2f(h2[k]) * w2; a3[k] += bf2f(h3[k]) * w3;
      }
    }
    for (; j < deg; j += 2){
      int jj = j + e2;
      if (jj < deg){
        int s = colS[wave][jj]; float w = wS[wave][jj];
        u16x8 hh = *(const u16x8*)(Hrow + (size_t)s * FDIM);
        #pragma unroll
        for (int k = 0; k < 8; ++k) a0[k] += bf2f(hh[k]) * w;
      }
    }
  } else {
    for (int j = e2; j < deg; j += 2){
      int s = col[start + j];
      float w = __expf(leaky(als[s] + adv));
      u16x8 hh = *(const u16x8*)(Hrow + (size_t)s * FDIM);
      #pragma unroll
      for (int k = 0; k < 8; ++k) a0[k] += bf2f(hh[k]) * w;
    }
  }
  float r[8];
  #pragma unroll
  for (int k = 0; k < 8; ++k){
    r[k] = (a0[k] + a1[k]) + (a2[k] + a3[k]);
    r[k] += __shfl_down(r[k], 32, 64);
  }
  if (t < 32){
    float4 bA = *(const float4*)(b + f);
    float4 bB = *(const float4*)(b + f + 4);
    float4 oA = make_float4(r[0]*inv + bA.x, r[1]*inv + bA.y, r[2]*inv + bA.z, r[3]*inv + bA.w);
    float4 oB = make_float4(r[4]*inv + bB.x, r[5]*inv + bB.y, r[6]*inv + bB.z, r[7]*inv + bB.w);
    *(float4*)(out + (size_t)i * FDIM + f) = oA;
    *(float4*)(out + (size_t)i * FDIM + f + 4) = oB;
  }
}

// ------------------------- launch -------------------------
extern "C" void kernel_launch(void* const* d_in, const int* in_sizes, int n_in,
                              void* d_out, int out_size, void* d_ws, size_t ws_size,
                              hipStream_t stream){
  const float* x   = (const float*)d_in[0];
  const int*   ei  = (const int*)d_in[1];
  const float* W1  = (const float*)d_in[2];
  const float* as1 = (const float*)d_in[3];
  const float* ad1 = (const float*)d_in[4];
  const float* b1  = (const float*)d_in[5];
  const float* W2  = (const float*)d_in[6];
  const float* as2 = (const float*)d_in[7];
  const float* ad2 = (const float*)d_in[8];
  const float* b2  = (const float*)d_in[9];
  float* out = (float*)d_out;

  int n = in_sizes[0] / IN_DIM;     // 50000
  int E = in_sizes[1] / 2;          // 800000
  int Mpad = (n + 127) & ~127;      // 50048
  const int* srcIdx = ei;
  const int* dstIdx = ei + E;

  char* ws = (char*)d_ws;
  size_t off = 0;
  auto alloc = [&](size_t bytes) -> void* {
    void* p = ws + off; off += (bytes + 255) & ~(size_t)255; return p;
  };
  unsigned short* bufA = (unsigned short*)alloc((size_t)Mpad * FDIM * 2);  // xb, then out1b
  unsigned short* bufB = (unsigned short*)alloc((size_t)Mpad * FDIM * 2);  // H1b, then H2b
  unsigned short* W1t  = (unsigned short*)alloc(256 * 256 * 2);
  unsigned short* W2t  = (unsigned short*)alloc(256 * 256 * 2);
  int*   tmp      = (int*)alloc((size_t)n * 4);
  int*   deg      = (int*)alloc((size_t)n * 4);
  int*   fill     = (int*)alloc((size_t)n * 4);
  int*   rowptr   = (int*)alloc((size_t)(n + 1) * 4);
  int*   partials = (int*)alloc(256 * 4);
  int*   col      = (int*)alloc((size_t)(E + n) * 4);
  float* als1     = (float*)alloc((size_t)n * HEADS * 4);
  float* ald1     = (float*)alloc((size_t)n * HEADS * 4);
  float* als2     = (float*)alloc((size_t)n * 4);
  float* ald2     = (float*)alloc((size_t)n * 4);
  (void)ws_size;

  // cooperative prep: zero + cast + W^T + CSR build
  int castUnits = Mpad * (FDIM / 4);
  void* args[] = { (void*)&x, (void*)&bufA, (void*)&castUnits, (void*)&n,
                   (void*)&W1, (void*)&W1t, (void*)&W2, (void*)&W2t,
                   (void*)&srcIdx, (void*)&dstIdx, (void*)&E, (void*)&n,
                   (void*)&deg, (void*)&fill, (void*)&tmp, (void*)&partials,
                   (void*)&rowptr, (void*)&col, (void*)&als2, (void*)&ald2 };
  hipLaunchCooperativeKernel((void*)k_coop, dim3(256), dim3(256), args, 0, stream);

  dim3 gg(Mpad / 128, FDIM / 128);
  int ga = (n + 3) / 4;
  // layer 1 (GEMM + fused als1/ald1)
  k_gemm<1><<<gg, 256, 0, stream>>>(bufA, W1t, bufB, as1, ad1, als1, ald1, n);
  k_agg1<<<ga, 256, 0, stream>>>(bufB, als1, ald1, rowptr, col, b1, bufA, n);  // out1b (ELU'd, bf16)
  // layer 2 (GEMM + fused als2/ald2 partials; als2/ald2 zeroed in k_coop)
  k_gemm<2><<<gg, 256, 0, stream>>>(bufA, W2t, bufB, as2, ad2, als2, ald2, n);
  k_agg2<<<ga, 256, 0, stream>>>(bufB, als2, ald2, rowptr, col, b2, out, n);
}

// Round 6
// 417.508 us; speedup vs baseline: 1.6780x; 1.6780x over previous
//
#include <hip/hip_runtime.h>
#include <math.h>

#define IN_DIM 256
#define FDIM 256      // HEADS*HID == OUT == 256
#define HEADS 4
#define NEG 0.2f
#define MAXD 96       // per-node staged edge cap; in-deg ~ Poisson(16)+1, P(>96) ~ 0

typedef __attribute__((ext_vector_type(8))) short bf16x8;
typedef __attribute__((ext_vector_type(8))) unsigned short u16x8;
typedef __attribute__((ext_vector_type(4))) float f32x4;

__device__ __forceinline__ float leaky(float x){ return x > 0.f ? x : NEG * x; }

__device__ __forceinline__ unsigned short f2bf(float f){
  unsigned int u = __float_as_uint(f);
  unsigned int r = u + 0x7fffu + ((u >> 16) & 1u);   // round-to-nearest-even
  return (unsigned short)(r >> 16);
}
__device__ __forceinline__ float bf2f(unsigned short s){
  return __uint_as_float(((unsigned int)s) << 16);
}

__device__ __forceinline__ float4 bcast4(float4 v){
  return make_float4(__shfl(v.x,0,64), __shfl(v.y,0,64), __shfl(v.z,0,64), __shfl(v.w,0,64));
}
__device__ __forceinline__ float comp4(float4 v, int h){
  return h==0 ? v.x : h==1 ? v.y : h==2 ? v.z : v.w;
}

__device__ __forceinline__ void gld_lds16(const void* g, void* l){
  __builtin_amdgcn_global_load_lds((const __attribute__((address_space(1))) unsigned int*)g,
                                   (__attribute__((address_space(3))) unsigned int*)l, 16, 0, 0);
}

// ------------------------- CSR build -------------------------
__global__ void k_hist(const int* __restrict__ dst, int* deg, int E){
  int e = blockIdx.x * blockDim.x + threadIdx.x;
  if (e < E) atomicAdd(&deg[dst[e]], 1);
}

__global__ void k_scanA(const int* __restrict__ deg, int* tmp, int* partials, int n){
  __shared__ int sm[256];
  int i = blockIdx.x * 256 + threadIdx.x;
  int v = (i < n) ? deg[i] + 1 : 0;     // +1: self loop
  sm[threadIdx.x] = v; __syncthreads();
  for (int off = 1; off < 256; off <<= 1){
    int x = (threadIdx.x >= off) ? sm[threadIdx.x - off] : 0;
    __syncthreads();
    sm[threadIdx.x] += x;
    __syncthreads();
  }
  if (i < n) tmp[i] = sm[threadIdx.x];            // inclusive within block
  if (threadIdx.x == 255) partials[blockIdx.x] = sm[255];
}

__global__ void k_scanB(int* partials, int nb){   // single block of 1024
  __shared__ int sm[1024];
  int t = threadIdx.x;
  int v = (t < nb) ? partials[t] : 0;
  sm[t] = v; __syncthreads();
  for (int off = 1; off < 1024; off <<= 1){
    int x = (t >= off) ? sm[t - off] : 0;
    __syncthreads();
    sm[t] += x;
    __syncthreads();
  }
  if (t < nb) partials[t] = sm[t] - v;            // exclusive
}

// also zeroes als2/ald2 (needed for k_gemm<2> atomic accumulation)
__global__ void k_scanC(const int* __restrict__ tmp, const int* __restrict__ deg,
                        const int* __restrict__ partials, int* rowptr, int n,
                        float* als2, float* ald2){
  int i = blockIdx.x * blockDim.x + threadIdx.x;
  if (i < n){
    int incl = tmp[i] + partials[i >> 8];
    rowptr[i] = incl - (deg[i] + 1);
    if (i == n - 1) rowptr[n] = incl;             // total = E + n
    als2[i] = 0.f; ald2[i] = 0.f;
  }
}

__global__ void k_fill(const int* __restrict__ src, const int* __restrict__ dst,
                       const int* __restrict__ rowptr, int* fill, int* col, int E, int n){
  int e = blockIdx.x * blockDim.x + threadIdx.x;
  if (e < E + n){
    int s, d;
    if (e < E){ s = src[e]; d = dst[e]; } else { s = d = e - E; }
    int pos = atomicAdd(&fill[d], 1);
    col[rowptr[d] + pos] = s;
  }
}

// ------------------------- fused: x fp32->bf16 cast (padded) + W1/W2 transpose-cast -------------------------
__global__ void k_castwt(const float* __restrict__ x, unsigned short* __restrict__ xb, int M, int castBlocks,
                         const float* __restrict__ W1, unsigned short* __restrict__ W1t,
                         const float* __restrict__ W2, unsigned short* __restrict__ W2t){
  int b = blockIdx.x;
  if (b < castBlocks){
    int idx = b * 256 + threadIdx.x;   // one ushort4 group per thread
    int row = idx >> 6;
    float4 v = make_float4(0.f, 0.f, 0.f, 0.f);
    if (row < M) v = *(const float4*)(x + (size_t)idx * 4);
    ushort4 o;
    o.x = f2bf(v.x); o.y = f2bf(v.y); o.z = f2bf(v.z); o.w = f2bf(v.w);
    *(ushort4*)(xb + (size_t)idx * 4) = o;
  } else {
    int bb = b - castBlocks;
    const float* W = (bb < 256) ? W1 : W2;
    unsigned short* Wt = (bb < 256) ? W1t : W2t;
    int nn = bb & 255, k = threadIdx.x;
    Wt[nn * 256 + k] = f2bf(W[k * 256 + nn]);
  }
}

// ------------------------- bf16 MFMA GEMM + fused attention logits -------------------------
// C[M,256] = A[M,256] @ Bt[256,256]^T; epilogue also computes als/ald row dots.
// L==1: by covers heads {2by, 2by+1}; round p == head 2by+p -> exact als1/ald1 write.
// L==2: single head over 256 cols -> atomicAdd partials into als2/ald2.
template<int L>
__global__ __launch_bounds__(256) void k_gemm(const unsigned short* __restrict__ A,
                                              const unsigned short* __restrict__ Bt,
                                              unsigned short* __restrict__ C,
                                              const float* __restrict__ avS, const float* __restrict__ avD,
                                              float* __restrict__ als, float* __restrict__ ald, int nvalid){
  __shared__ __align__(16) unsigned short sh[8192];   // As = sh[0:4096], Bs = sh[4096:8192] (shorts)
  unsigned short* As = sh;
  unsigned short* Bs = sh + 4096;
  int tid = threadIdx.x;
  int lane = tid & 63, wave = tid >> 6;
  int rowBase = blockIdx.x * 128, colBase = blockIdx.y * 128;
  int wr = (wave & 1) * 64, wc = (wave >> 1) * 64;

  f32x4 acc[4][4] = {};
  int c0 = tid, c1 = tid + 256;
  int r0 = c0 >> 2, kc0 = (c0 & 3) * 8;
  int r1 = c1 >> 2, kc1 = (c1 & 3) * 8;
  int m0 = lane & 15, kq = (lane >> 4) * 8;

  for (int k0 = 0; k0 < 256; k0 += 32){
    gld_lds16(A  + (size_t)(rowBase + r0) * 256 + k0 + kc0, (char*)As + c0 * 16);
    gld_lds16(A  + (size_t)(rowBase + r1) * 256 + k0 + kc1, (char*)As + c1 * 16);
    gld_lds16(Bt + (size_t)(colBase + r0) * 256 + k0 + kc0, (char*)Bs + c0 * 16);
    gld_lds16(Bt + (size_t)(colBase + r1) * 256 + k0 + kc1, (char*)Bs + c1 * 16);
    __syncthreads();
    bf16x8 af[4], bfr[4];
    #pragma unroll
    for (int it = 0; it < 4; ++it)
      af[it] = *(const bf16x8*)(As + (wr + it * 16 + m0) * 32 + kq);
    #pragma unroll
    for (int jt = 0; jt < 4; ++jt)
      bfr[jt] = *(const bf16x8*)(Bs + (wc + jt * 16 + m0) * 32 + kq);
    #pragma unroll
    for (int it = 0; it < 4; ++it)
      #pragma unroll
      for (int jt = 0; jt < 4; ++jt)
        acc[it][jt] = __builtin_amdgcn_mfma_f32_16x16x32_bf16(af[it], bfr[jt], acc[it][jt], 0, 0, 0);
    __syncthreads();
  }
  // epilogue: repack C/D frags (col=lane&15, row=(lane>>4)*4+reg) through LDS.
  int cq = lane >> 4, cm = lane & 15;
  #pragma unroll
  for (int p = 0; p < 2; ++p){
    if ((wave >> 1) == p){
      #pragma unroll
      for (int it = 0; it < 4; ++it)
        #pragma unroll
        for (int jt = 0; jt < 4; ++jt)
          #pragma unroll
          for (int r = 0; r < 4; ++r)
            sh[(wr + it * 16 + cq * 4 + r) * 64 + jt * 16 + cm] = f2bf(acc[it][jt][r]);
    }
    __syncthreads();
    // fused attention logits: 2 threads per row, 32 cols each
    {
      int r = tid >> 1, half = tid & 1;
      int rg = rowBase + r;
      const float* aS;
      const float* aD;
      if (L == 1){ aS = avS + (blockIdx.y * 2 + p) * 64; aD = avD + (blockIdx.y * 2 + p) * 64; }
      else       { aS = avS + colBase + p * 64;          aD = avD + colBase + p * 64; }
      float ps = 0.f, pd = 0.f;
      #pragma unroll
      for (int k4 = 0; k4 < 8; ++k4){
        ushort4 hv = *(const ushort4*)(sh + r * 64 + half * 32 + k4 * 4);
        float4 a4 = *(const float4*)(aS + half * 32 + k4 * 4);
        float4 d4 = *(const float4*)(aD + half * 32 + k4 * 4);
        ps += bf2f(hv.x)*a4.x + bf2f(hv.y)*a4.y + bf2f(hv.z)*a4.z + bf2f(hv.w)*a4.w;
        pd += bf2f(hv.x)*d4.x + bf2f(hv.y)*d4.y + bf2f(hv.z)*d4.z + bf2f(hv.w)*d4.w;
      }
      ps += __shfl_xor(ps, 1, 64);
      pd += __shfl_xor(pd, 1, 64);
      if (half == 0 && rg < nvalid){
        if (L == 1){
          als[rg * 4 + blockIdx.y * 2 + p] = ps;
          ald[rg * 4 + blockIdx.y * 2 + p] = pd;
        } else {
          atomicAdd(&als[rg], ps);
          atomicAdd(&ald[rg], pd);
        }
      }
    }
    // C store: 128 rows x 8 segments of 8 shorts = 1024 segments; 256 threads x 4 rounds
    #pragma unroll
    for (int q = 0; q < 4; ++q){
      int id = tid + q * 256;
      int r = id >> 3, sg = id & 7;
      u16x8 v = *(const u16x8*)(sh + r * 64 + sg * 8);
      *(u16x8*)(C + (size_t)(rowBase + r) * 256 + colBase + p * 64 + sg * 8) = v;
    }
    __syncthreads();
  }
}

// ------------------------- layer-1 aggregation: 4 nodes/block, wave per node -------------------------
// softmax without max-subtraction (logits ~ +-3 here; mathematically identical)
__global__ __launch_bounds__(256) void k_agg1(const unsigned short* __restrict__ Hb,
    const float* __restrict__ als, const float* __restrict__ ald,
    const int* __restrict__ rowptr, const int* __restrict__ col,
    const float* __restrict__ b, unsigned short* __restrict__ outb, int n){
  __shared__ __align__(16) int   colS[4][MAXD];
  __shared__ __align__(16) float wS[4][MAXD][4];
  int wave = threadIdx.x >> 6, t = threadIdx.x & 63;
  int i = blockIdx.x * 4 + wave; if (i >= n) i = n - 1;
  int start = rowptr[i];
  int deg = rowptr[i + 1] - start;
  float4 adv = *(const float4*)(ald + (size_t)i * 4);
  bool staged = (deg <= MAXD);

  // phase A: stage col + softmax weights, accumulate per-head sums
  float4 ls = make_float4(0.f, 0.f, 0.f, 0.f);
  if (staged){
    for (int j = t; j < deg; j += 64){
      int s = col[start + j];
      colS[wave][j] = s;
      float4 a = *(const float4*)(als + (size_t)s * 4);
      float4 w = make_float4(__expf(leaky(a.x + adv.x)), __expf(leaky(a.y + adv.y)),
                             __expf(leaky(a.z + adv.z)), __expf(leaky(a.w + adv.w)));
      *(float4*)(&wS[wave][j][0]) = w;
      ls.x += w.x; ls.y += w.y; ls.z += w.z; ls.w += w.w;
    }
  } else {
    for (int j = t; j < deg; j += 64){
      int s = col[start + j];
      float4 a = *(const float4*)(als + (size_t)s * 4);
      ls.x += __expf(leaky(a.x + adv.x)); ls.y += __expf(leaky(a.y + adv.y));
      ls.z += __expf(leaky(a.z + adv.z)); ls.w += __expf(leaky(a.w + adv.w));
    }
  }
  #pragma unroll
  for (int off = 32; off >= 1; off >>= 1) ls = make_float4(
      ls.x + __shfl_down(ls.x, off, 64), ls.y + __shfl_down(ls.y, off, 64),
      ls.z + __shfl_down(ls.z, off, 64), ls.w + __shfl_down(ls.w, off, 64));
  float4 d4 = bcast4(ls);
  __syncthreads();

  // phase C: half-wave per edge, 8 feats/lane, 4 loads in flight
  int e2 = t >> 5, l32 = t & 31;
  int h = l32 >> 3, f = l32 * 8;
  float inv = 1.f / (comp4(d4, h) + 1e-16f);
  const unsigned short* Hrow = Hb + f;
  float a0[8] = {0,0,0,0,0,0,0,0}, a1[8] = {0,0,0,0,0,0,0,0};
  float a2[8] = {0,0,0,0,0,0,0,0}, a3[8] = {0,0,0,0,0,0,0,0};
  if (staged){
    int j = 0;
    for (; j + 7 < deg; j += 8){
      int j0 = j + e2, j1 = j + 2 + e2, j2 = j + 4 + e2, j3 = j + 6 + e2;
      int s0 = colS[wave][j0], s1 = colS[wave][j1], s2 = colS[wave][j2], s3 = colS[wave][j3];
      float w0 = wS[wave][j0][h], w1 = wS[wave][j1][h], w2 = wS[wave][j2][h], w3 = wS[wave][j3][h];
      u16x8 h0 = *(const u16x8*)(Hrow + (size_t)s0 * FDIM);
      u16x8 h1 = *(const u16x8*)(Hrow + (size_t)s1 * FDIM);
      u16x8 h2 = *(const u16x8*)(Hrow + (size_t)s2 * FDIM);
      u16x8 h3 = *(const u16x8*)(Hrow + (size_t)s3 * FDIM);
      #pragma unroll
      for (int k = 0; k < 8; ++k){
        a0[k] += bf2f(h0[k]) * w0; a1[k] += bf2f(h1[k]) * w1;
        a2[k] += bf2f(h2[k]) * w2; a3[k] += bf2f(h3[k]) * w3;
      }
    }
    for (; j < deg; j += 2){
      int jj = j + e2;
      if (jj < deg){
        int s = colS[wave][jj]; float w = wS[wave][jj][h];
        u16x8 hh = *(const u16x8*)(Hrow + (size_t)s * FDIM);
        #pragma unroll
        for (int k = 0; k < 8; ++k) a0[k] += bf2f(hh[k]) * w;
      }
    }
  } else {
    float adh = comp4(adv, h);
    for (int j = e2; j < deg; j += 2){
      int s = col[start + j];
      float w = __expf(leaky(als[(size_t)s * 4 + h] + adh));
      u16x8 hh = *(const u16x8*)(Hrow + (size_t)s * FDIM);
      #pragma unroll
      for (int k = 0; k < 8; ++k) a0[k] += bf2f(hh[k]) * w;
    }
  }
  float r[8];
  #pragma unroll
  for (int k = 0; k < 8; ++k){
    r[k] = (a0[k] + a1[k]) + (a2[k] + a3[k]);
    r[k] += __shfl_down(r[k], 32, 64);
  }
  if (t < 32){
    float4 bA = *(const float4*)(b + f);
    float4 bB = *(const float4*)(b + f + 4);
    float bb[8] = {bA.x, bA.y, bA.z, bA.w, bB.x, bB.y, bB.z, bB.w};
    u16x8 o;
    #pragma unroll
    for (int k = 0; k < 8; ++k){
      float v = r[k] * inv + bb[k];
      v = (v > 0.f) ? v : (__expf(v) - 1.f);    // ELU
      o[k] = f2bf(v);
    }
    *(u16x8*)(outb + (size_t)i * FDIM + f) = o;
  }
}

// ------------------------- layer-2 aggregation: 4 nodes/block, wave per node, fp32 out -------------------------
__global__ __launch_bounds__(256) void k_agg2(const unsigned short* __restrict__ Hb,
    const float* __restrict__ als, const float* __restrict__ ald,
    const int* __restrict__ rowptr, const int* __restrict__ col,
    const float* __restrict__ b, float* __restrict__ out, int n){
  __shared__ __align__(16) int   colS[4][MAXD];
  __shared__ __align__(16) float wS[4][MAXD];
  int wave = threadIdx.x >> 6, t = threadIdx.x & 63;
  int i = blockIdx.x * 4 + wave; if (i >= n) i = n - 1;
  int start = rowptr[i];
  int deg = rowptr[i + 1] - start;
  float adv = ald[i];
  bool staged = (deg <= MAXD);

  float ls = 0.f;
  if (staged){
    for (int j = t; j < deg; j += 64){
      int s = col[start + j];
      colS[wave][j] = s;
      float w = __expf(leaky(als[s] + adv));
      wS[wave][j] = w;
      ls += w;
    }
  } else {
    for (int j = t; j < deg; j += 64) ls += __expf(leaky(als[col[start + j]] + adv));
  }
  #pragma unroll
  for (int off = 32; off >= 1; off >>= 1) ls += __shfl_down(ls, off, 64);
  float inv = 1.f / (__shfl(ls, 0, 64) + 1e-16f);
  __syncthreads();

  int e2 = t >> 5, l32 = t & 31;
  int f = l32 * 8;
  const unsigned short* Hrow = Hb + f;
  float a0[8] = {0,0,0,0,0,0,0,0}, a1[8] = {0,0,0,0,0,0,0,0};
  float a2[8] = {0,0,0,0,0,0,0,0}, a3[8] = {0,0,0,0,0,0,0,0};
  if (staged){
    int j = 0;
    for (; j + 7 < deg; j += 8){
      int j0 = j + e2, j1 = j + 2 + e2, j2 = j + 4 + e2, j3 = j + 6 + e2;
      int s0 = colS[wave][j0], s1 = colS[wave][j1], s2 = colS[wave][j2], s3 = colS[wave][j3];
      float w0 = wS[wave][j0], w1 = wS[wave][j1], w2 = wS[wave][j2], w3 = wS[wave][j3];
      u16x8 h0 = *(const u16x8*)(Hrow + (size_t)s0 * FDIM);
      u16x8 h1 = *(const u16x8*)(Hrow + (size_t)s1 * FDIM);
      u16x8 h2 = *(const u16x8*)(Hrow + (size_t)s2 * FDIM);
      u16x8 h3 = *(const u16x8*)(Hrow + (size_t)s3 * FDIM);
      #pragma unroll
      for (int k = 0; k < 8; ++k){
        a0[k] += bf2f(h0[k]) * w0; a1[k] += bf2f(h1[k]) * w1;
        a2[k] += bf2f(h2[k]) * w2; a3[k] += bf2f(h3[k]) * w3;
      }
    }
    for (; j < deg; j += 2){
      int jj = j + e2;
      if (jj < deg){
        int s = colS[wave][jj]; float w = wS[wave][jj];
        u16x8 hh = *(const u16x8*)(Hrow + (size_t)s * FDIM);
        #pragma unroll
        for (int k = 0; k < 8; ++k) a0[k] += bf2f(hh[k]) * w;
      }
    }
  } else {
    for (int j = e2; j < deg; j += 2){
      int s = col[start + j];
      float w = __expf(leaky(als[s] + adv));
      u16x8 hh = *(const u16x8*)(Hrow + (size_t)s * FDIM);
      #pragma unroll
      for (int k = 0; k < 8; ++k) a0[k] += bf2f(hh[k]) * w;
    }
  }
  float r[8];
  #pragma unroll
  for (int k = 0; k < 8; ++k){
    r[k] = (a0[k] + a1[k]) + (a2[k] + a3[k]);
    r[k] += __shfl_down(r[k], 32, 64);
  }
  if (t < 32){
    float4 bA = *(const float4*)(b + f);
    float4 bB = *(const float4*)(b + f + 4);
    float4 oA = make_float4(r[0]*inv + bA.x, r[1]*inv + bA.y, r[2]*inv + bA.z, r[3]*inv + bA.w);
    float4 oB = make_float4(r[4]*inv + bB.x, r[5]*inv + bB.y, r[6]*inv + bB.z, r[7]*inv + bB.w);
    *(float4*)(out + (size_t)i * FDIM + f) = oA;
    *(float4*)(out + (size_t)i * FDIM + f + 4) = oB;
  }
}

// ------------------------- launch -------------------------
extern "C" void kernel_launch(void* const* d_in, const int* in_sizes, int n_in,
                              void* d_out, int out_size, void* d_ws, size_t ws_size,
                              hipStream_t stream){
  const float* x   = (const float*)d_in[0];
  const int*   ei  = (const int*)d_in[1];
  const float* W1  = (const float*)d_in[2];
  const float* as1 = (const float*)d_in[3];
  const float* ad1 = (const float*)d_in[4];
  const float* b1  = (const float*)d_in[5];
  const float* W2  = (const float*)d_in[6];
  const float* as2 = (const float*)d_in[7];
  const float* ad2 = (const float*)d_in[8];
  const float* b2  = (const float*)d_in[9];
  float* out = (float*)d_out;

  int n = in_sizes[0] / IN_DIM;     // 50000
  int E = in_sizes[1] / 2;          // 800000
  int Mpad = (n + 127) & ~127;      // 50048
  const int* srcIdx = ei;
  const int* dstIdx = ei + E;

  char* ws = (char*)d_ws;
  size_t off = 0;
  auto alloc = [&](size_t bytes) -> void* {
    void* p = ws + off; off += (bytes + 255) & ~(size_t)255; return p;
  };
  unsigned short* bufA = (unsigned short*)alloc((size_t)Mpad * FDIM * 2);  // xb, then out1b
  unsigned short* bufB = (unsigned short*)alloc((size_t)Mpad * FDIM * 2);  // H1b, then H2b
  unsigned short* W1t  = (unsigned short*)alloc(256 * 256 * 2);
  unsigned short* W2t  = (unsigned short*)alloc(256 * 256 * 2);
  int*   tmp      = (int*)alloc((size_t)n * 4);
  int*   deg      = (int*)alloc((size_t)n * 4);
  int*   fill     = (int*)alloc((size_t)n * 4);
  int*   rowptr   = (int*)alloc((size_t)(n + 1) * 4);
  int*   partials = (int*)alloc(1024 * 4);
  int*   col      = (int*)alloc((size_t)(E + n) * 4);
  float* als1     = (float*)alloc((size_t)n * HEADS * 4);
  float* ald1     = (float*)alloc((size_t)n * HEADS * 4);
  float* als2     = (float*)alloc((size_t)n * 4);
  float* ald2     = (float*)alloc((size_t)n * 4);
  (void)ws_size;

  int nb = (n + 255) / 256;
  // CSR build (deg and fill are adjacent in ws -> one memset spans both)
  hipMemsetAsync(deg, 0, (size_t)((char*)fill - (char*)deg) + (size_t)n * 4, stream);
  k_hist<<<(E + 255) / 256, 256, 0, stream>>>(dstIdx, deg, E);
  k_scanA<<<nb, 256, 0, stream>>>(deg, tmp, partials, n);
  k_scanB<<<1, 1024, 0, stream>>>(partials, nb);
  k_scanC<<<nb, 256, 0, stream>>>(tmp, deg, partials, rowptr, n, als2, ald2);
  k_fill<<<(E + n + 255) / 256, 256, 0, stream>>>(srcIdx, dstIdx, rowptr, fill, col, E, n);

  // fused cast + weight transposes
  int castBlocks = (Mpad * (FDIM / 4) + 255) / 256;
  k_castwt<<<castBlocks + 512, 256, 0, stream>>>(x, bufA, n, castBlocks, W1, W1t, W2, W2t);

  dim3 gg(Mpad / 128, FDIM / 128);
  int ga = (n + 3) / 4;
  // layer 1 (GEMM + fused als1/ald1)
  k_gemm<1><<<gg, 256, 0, stream>>>(bufA, W1t, bufB, as1, ad1, als1, ald1, n);
  k_agg1<<<ga, 256, 0, stream>>>(bufB, als1, ald1, rowptr, col, b1, bufA, n);  // out1b (ELU'd, bf16)
  // layer 2 (GEMM + fused als2/ald2 partials)
  k_gemm<2><<<gg, 256, 0, stream>>>(bufA, W2t, bufB, as2, ad2, als2, ald2, n);
  k_agg2<<<ga, 256, 0, stream>>>(bufB, als2, ald2, rowptr, col, b2, out, n);
}